// Round 5
// baseline (416.465 us; speedup 1.0000x reference)
//
#include <hip/hip_runtime.h>

typedef float f32x4 __attribute__((ext_vector_type(4)));

#define M_ROWS 131072
#define N_COLS 512
#define K_DIM  64
#define MCHUNK 128   // m rows per block

// 0.5*tanh(p) = 0.5 - 1/(exp2(p*2*log2 e)+1); exact at 0, saturates correctly.
__device__ __forceinline__ float half_tanh(float p) {
  float t = __builtin_amdgcn_exp2f(p * 2.8853900817779268f);
  return 0.5f - __builtin_amdgcn_rcpf(t + 1.0f);
}

__global__ __launch_bounds__(256, 4) void esn_valu(const float* __restrict__ x,
                                                   const float* __restrict__ w,
                                                   float* __restrict__ out) {
  const int tid = threadIdx.x;
  const int r = blockIdx.y * 256 + tid;   // this lane's output column

  // ---- w row: 64 floats, MUST stay in VGPRs (pinned in-loop below) ----
  f32x4 wr[16];
  const f32x4* wp = (const f32x4*)(w + (size_t)r * K_DIM);
#pragma unroll
  for (int i = 0; i < 16; ++i) wr[i] = wp[i];

  const int m0 = blockIdx.x * MCHUNK;
  const f32x4* xrow = (const f32x4*)(x + (size_t)m0 * K_DIM);  // 16 f32x4 / row
  float* orow = out + (size_t)m0 * N_COLS + r;

  // quarter buffers: 4 f32x4 each (16 k-values)
  f32x4 a0 = xrow[0], a1 = xrow[1], a2 = xrow[2], a3 = xrow[3];  // row0 q0
  f32x4 b0, b1, b2, b3;

#pragma unroll 1
  for (int mi = 0; mi < MCHUNK; ++mi) {
    // Pin w every iteration: values must be register-resident at each
    // iteration boundary -> allocator must keep them live in VGPRs.
#pragma unroll
    for (int i = 0; i < 16; ++i) asm volatile("" : "+v"(wr[i]));

    const f32x4* xq = xrow + (size_t)mi * 16;
    const f32x4* xn = xrow + ((mi == MCHUNK - 1) ? 0 : (size_t)(mi + 1) * 16);
    f32x4 acc = {0.f, 0.f, 0.f, 0.f};

#define FMA_Q(B0, B1, B2, B3, W)                                   \
  do {                                                             \
    _Pragma("unroll") for (int j = 0; j < 4; ++j) {                \
      acc[0] = fmaf((B0)[j], wr[(W) + 0][j], acc[0]);              \
      acc[1] = fmaf((B1)[j], wr[(W) + 1][j], acc[1]);              \
      acc[2] = fmaf((B2)[j], wr[(W) + 2][j], acc[2]);              \
      acc[3] = fmaf((B3)[j], wr[(W) + 3][j], acc[3]);              \
    }                                                              \
  } while (0)

    // q0: prefetch q1 -> B, compute q0 from A
    b0 = xq[4]; b1 = xq[5]; b2 = xq[6]; b3 = xq[7];
    FMA_Q(a0, a1, a2, a3, 0);
    // q1: prefetch q2 -> A, compute q1 from B
    a0 = xq[8]; a1 = xq[9]; a2 = xq[10]; a3 = xq[11];
    FMA_Q(b0, b1, b2, b3, 4);
    // q2: prefetch q3 -> B, compute q2 from A
    b0 = xq[12]; b1 = xq[13]; b2 = xq[14]; b3 = xq[15];
    FMA_Q(a0, a1, a2, a3, 8);
    // q3: prefetch next row q0 -> A, compute q3 from B
    a0 = xn[0]; a1 = xn[1]; a2 = xn[2]; a3 = xn[3];
    FMA_Q(b0, b1, b2, b3, 12);
#undef FMA_Q

    const float v = half_tanh((acc[0] + acc[1]) + (acc[2] + acc[3]));
    orow[(size_t)mi * N_COLS] = v;
  }
}

extern "C" void kernel_launch(void* const* d_in, const int* in_sizes, int n_in,
                              void* d_out, int out_size, void* d_ws, size_t ws_size,
                              hipStream_t stream) {
  const float* x = (const float*)d_in[0];   // [131072, 64]
  const float* w = (const float*)d_in[1];   // [512, 64]
  // d_in[2] (d) is dead: reference state is identically zero.
  float* out = (float*)d_out;               // [131072, 512]

  dim3 grid(M_ROWS / MCHUNK, 2);   // (1024, 2)
  dim3 block(256);                 // 4 waves; r = blockIdx.y*256 + tid
  hipLaunchKernelGGL(esn_valu, grid, block, 0, stream, x, w, out);
}

// Round 6
// 312.742 us; speedup vs baseline: 1.3317x; 1.3317x over previous
//
#include <hip/hip_runtime.h>

typedef float f32x4 __attribute__((ext_vector_type(4)));

#define M_ROWS 131072
#define N_COLS 512
#define K_DIM  64
#define MCHUNK 128   // m rows per block

// 0.5*tanh(p) = 0.5 - 1/(exp2(p*2*log2 e)+1); exact at 0, saturates correctly.
__device__ __forceinline__ float half_tanh(float p) {
  float t = __builtin_amdgcn_exp2f(p * 2.8853900817779268f);
  return 0.5f - __builtin_amdgcn_rcpf(t + 1.0f);
}

__global__ __launch_bounds__(256, 3) void esn_valu(const float* __restrict__ x,
                                                   const float* __restrict__ w,
                                                   float* __restrict__ out) {
  const int tid = threadIdx.x;
  const int r = blockIdx.y * 256 + tid;   // this lane's output column

  // ---- w row (64 floats) via inline-asm loads ----
  // Rounds 3-5: plain loads of w were REMATERIALIZED into the k-loop
  // (VGPR_Count stuck at 36-40, w re-fetched as a 256B-stride gather every
  // iteration). Asm outputs cannot be recomputed -> they must stay in VGPRs.
  f32x4 wq[16];
  {
    const float* wrow = w + (size_t)r * K_DIM;
#pragma unroll
    for (int i = 0; i < 16; ++i)
      asm volatile("global_load_dwordx4 %0, %1, off"
                   : "=v"(wq[i])
                   : "v"(wrow + i * 4)
                   : "memory");
    asm volatile("s_waitcnt vmcnt(0)" ::: "memory");
    __builtin_amdgcn_sched_barrier(0);   // rule #18: no consumer hoists above the wait
  }

  const int m0 = blockIdx.x * MCHUNK;
  const f32x4* xrow = (const f32x4*)(x + (size_t)m0 * K_DIM);  // 16 f32x4 / row
  float* orow = out + (size_t)m0 * N_COLS + r;

  // x quarter-buffers (4 f32x4 = 16 k-values), double-buffered
  f32x4 a0 = xrow[0], a1 = xrow[1], a2 = xrow[2], a3 = xrow[3];  // row0 q0
  f32x4 b0, b1, b2, b3;

#pragma unroll 1
  for (int mi = 0; mi < MCHUNK; ++mi) {
    const f32x4* xq = xrow + (size_t)mi * 16;
    const f32x4* xn = xrow + ((mi == MCHUNK - 1) ? 0 : (size_t)(mi + 1) * 16);
    f32x4 acc = {0.f, 0.f, 0.f, 0.f};

#define FMA_Q(B0, B1, B2, B3, W)                                   \
  do {                                                             \
    _Pragma("unroll") for (int j = 0; j < 4; ++j) {                \
      acc[0] = fmaf((B0)[j], wq[(W) + 0][j], acc[0]);              \
      acc[1] = fmaf((B1)[j], wq[(W) + 1][j], acc[1]);              \
      acc[2] = fmaf((B2)[j], wq[(W) + 2][j], acc[2]);              \
      acc[3] = fmaf((B3)[j], wq[(W) + 3][j], acc[3]);              \
    }                                                              \
  } while (0)

    // q0: prefetch q1 -> B, compute q0 from A
    b0 = xq[4]; b1 = xq[5]; b2 = xq[6]; b3 = xq[7];
    FMA_Q(a0, a1, a2, a3, 0);
    // q1: prefetch q2 -> A, compute q1 from B
    a0 = xq[8]; a1 = xq[9]; a2 = xq[10]; a3 = xq[11];
    FMA_Q(b0, b1, b2, b3, 4);
    // q2: prefetch q3 -> B, compute q2 from A
    b0 = xq[12]; b1 = xq[13]; b2 = xq[14]; b3 = xq[15];
    FMA_Q(a0, a1, a2, a3, 8);
    // q3: prefetch next row q0 -> A, compute q3 from B
    a0 = xn[0]; a1 = xn[1]; a2 = xn[2]; a3 = xn[3];
    FMA_Q(b0, b1, b2, b3, 12);
#undef FMA_Q

    orow[(size_t)mi * N_COLS] = half_tanh((acc[0] + acc[1]) + (acc[2] + acc[3]));
  }
}

extern "C" void kernel_launch(void* const* d_in, const int* in_sizes, int n_in,
                              void* d_out, int out_size, void* d_ws, size_t ws_size,
                              hipStream_t stream) {
  const float* x = (const float*)d_in[0];   // [131072, 64]
  const float* w = (const float*)d_in[1];   // [512, 64]
  // d_in[2] (d) is dead: reference state is identically zero.
  float* out = (float*)d_out;               // [131072, 512]

  dim3 grid(M_ROWS / MCHUNK, 2);   // (1024, 2)
  dim3 block(256);                 // 4 waves; r = blockIdx.y*256 + tid
  hipLaunchKernelGGL(esn_valu, grid, block, 0, stream, x, w, out);
}